// Round 7
// baseline (446.067 us; speedup 1.0000x reference)
//
#include <hip/hip_runtime.h>
#include <math.h>

#define FIN 512
#define FH 128
#define FOUT 40
#define FP 64   // padded H2 width

typedef __attribute__((ext_vector_type(8))) short bf16x8;
typedef __attribute__((ext_vector_type(4))) float f32x4;

__device__ inline ushort f2bf(float f){
  union { float f; uint32_t u; } v; v.f = f;
  uint32_t u = v.u;
  uint32_t r = (u + 0x7FFF + ((u >> 16) & 1)) >> 16;
  return (ushort)r;
}
__device__ inline uint32_t pk(float a, float b){ return (uint32_t)f2bf(a) | ((uint32_t)f2bf(b) << 16); }

// ---------------- CSR build ----------------

// zero cnt+cursor AND prep weights in one launch
__global__ void k_init(int* __restrict__ p, int n2,
                       const float* __restrict__ W1, const float* __restrict__ W2,
                       ushort* __restrict__ W1t, ushort* __restrict__ W2t){
  int i = blockIdx.x*256 + threadIdx.x;
  if(i<n2) p[i]=0;
  if(i < FIN*FH){
    int k = i / FH, c = i % FH;
    W1t[(size_t)c*FIN + k] = f2bf(W1[i]);
  }
  if(i < 48*FH){
    int c = i / FH, k = i % FH;
    W2t[i] = (c < FOUT) ? f2bf(W2[(size_t)k*FOUT + c]) : (ushort)0;
  }
}

__global__ void k_count(const int* __restrict__ dst, int e, int* __restrict__ cnt){
  int i = blockIdx.x*256 + threadIdx.x;
  if(i<e) atomicAdd(&cnt[dst[i]],1);
}

__global__ void k_scan_a(const int* __restrict__ cnt, int n, int* __restrict__ rp, int* __restrict__ aux){
  __shared__ int sh[256];
  int t = threadIdx.x;
  int base = blockIdx.x*1024;
  int v[4]; int s = 0;
  #pragma unroll
  for(int j=0;j<4;j++){ int idx = base + t*4 + j; int x = (idx<n)?cnt[idx]:0; v[j]=x; s+=x; }
  sh[t]=s; __syncthreads();
  for(int off=1; off<256; off<<=1){
    int x = (t>=off)? sh[t-off]:0; __syncthreads();
    sh[t]+=x; __syncthreads();
  }
  int run = (t>0)? sh[t-1]:0;
  #pragma unroll
  for(int j=0;j<4;j++){ run += v[j]; int idx = base + t*4 + j; if(idx<n) rp[idx+1]=run; }
  if(t==255) aux[blockIdx.x]=sh[255];
}

__global__ void k_scan_b(int* __restrict__ aux, int nchunks){
  __shared__ int sh[256];
  int t = threadIdx.x;
  sh[t] = (t<nchunks)? aux[t] : 0;
  __syncthreads();
  for(int off=1; off<256; off<<=1){
    int x = (t>=off)? sh[t-off]:0; __syncthreads();
    sh[t]+=x; __syncthreads();
  }
  if(t<nchunks) aux[t] = (t>0)? sh[t-1] : 0;
}

__global__ void k_scan_c(int* __restrict__ rp, const int* __restrict__ aux,
                         const int* __restrict__ cnt, float* __restrict__ dinv, int n){
  int i = blockIdx.x*256 + threadIdx.x;
  if(i<n){
    rp[i+1] += aux[i>>10];
    dinv[i] = rsqrtf((float)(cnt[i]+1));
  }
  if(i==0) rp[0] = 0;
}

__global__ void k_fill(const int* __restrict__ src, const int* __restrict__ dst, int e,
                       const int* __restrict__ rp, int* __restrict__ cursor, int* __restrict__ srcs){
  int i = blockIdx.x*256 + threadIdx.x;
  if(i<e){
    int d = dst[i];
    int p = rp[d] + atomicAdd(&cursor[d],1);
    srcs[p] = src[i];
  }
}

// ---------------- GEMM1 via MFMA, W1 staged in LDS (four 32KB K-phases) ----------------
// 256 thr = 4 waves x 16 rows = 64 rows/block; B frags from swizzled LDS, A streamed.
__global__ __launch_bounds__(256, 2) void k_gemm1_mfma(const float* __restrict__ X,
                                                       const ushort* __restrict__ W1t,
                                                       const float* __restrict__ dinv,
                                                       float* __restrict__ XWf, int n){
  __shared__ ushort Ws[FH * 128];   // 32 KB: [128 cols][128 k] bf16, XOR-swizzled
  int t = threadIdx.x;
  int lane = t & 63;
  int wid = t >> 6;
  int l15 = lane & 15;
  int lk8 = (lane >> 4) * 8;
  int rowbase = blockIdx.x * 64 + wid * 16;

  int r0 = rowbase + l15; if (r0 >= n) r0 = n-1;
  const float* ap = X + (size_t)r0*FIN;

  f32x4 acc[8];
  #pragma unroll
  for(int j=0;j<8;j++) acc[j] = (f32x4){0.f,0.f,0.f,0.f};

  char* WsB = (char*)Ws;

  for(int ph=0; ph<4; ph++){
    if(ph) __syncthreads();
    // stage 32KB: 2048 uint4 chunks, 256 thr -> 8 iters
    #pragma unroll
    for(int it=0; it<8; it++){
      int c = it*256 + t;
      int col = c >> 4, kslot = c & 15;
      uint4 v = *(const uint4*)(W1t + (size_t)col*FIN + ph*128 + kslot*8);
      int dstb = col*256 + ((kslot*16) ^ ((col & 7) << 4));
      *(uint4*)(WsB + dstb) = v;
    }
    __syncthreads();

    #pragma unroll
    for(int kc=0; kc<4; kc++){
      int kl = kc*32 + lk8;             // local k within phase
      int kg = ph*128 + kl;             // global k
      float4 aa = *(const float4*)(ap + kg);
      float4 ab = *(const float4*)(ap + kg + 4);
      bf16x8 fa;
      fa[0]=(short)f2bf(aa.x); fa[1]=(short)f2bf(aa.y); fa[2]=(short)f2bf(aa.z); fa[3]=(short)f2bf(aa.w);
      fa[4]=(short)f2bf(ab.x); fa[5]=(short)f2bf(ab.y); fa[6]=(short)f2bf(ab.z); fa[7]=(short)f2bf(ab.w);

      #pragma unroll
      for(int fj=0; fj<8; fj++){
        int col = fj*16 + l15;
        int srcb = col*256 + ((kl*2) ^ ((col & 7) << 4));
        bf16x8 fb = *(const bf16x8*)(WsB + srcb);
        acc[fj] = __builtin_amdgcn_mfma_f32_16x16x32_bf16(fa, fb, acc[fj], 0, 0, 0);
      }
    }
  }

  int rbase = (lane >> 4) * 4;
  #pragma unroll
  for(int r=0; r<4; r++){
    int row = rowbase + rbase + r;
    if(row < n){
      float dd = dinv[row];
      #pragma unroll
      for(int fj=0; fj<8; fj++){
        XWf[(size_t)row*FH + fj*16 + l15] = acc[fj][r] * dd;
      }
    }
  }
}

// ---------------- agg1: H1b = relu(dd*(sum_s XWf[s] + XWf[d]) + b1), bf16 out ----------------
// wave per node; 8 groups x 8 lanes; fp32 gather (4 x float4 / lane), 2-edge unroll.
__global__ __launch_bounds__(256) void k_agg1(const float* __restrict__ XWf, const int* __restrict__ rp,
                                              const int* __restrict__ srcs, const float* __restrict__ dinv,
                                              const float* __restrict__ b1, ushort* __restrict__ H1b, int n){
  int d = blockIdx.x*4 + (threadIdx.x >> 6);
  if(d >= n) return;
  int lane = threadIdx.x & 63;
  int g = lane >> 3, li = lane & 7;
  float acc[16];
  #pragma unroll
  for(int k=0;k<16;k++) acc[k]=0.f;
  int beg = rp[d], end = rp[d+1];
  int j = beg + g;
  for(; j + 8 < end; j += 16){
    int s0 = srcs[j];
    int s1 = srcs[j+8];
    const float4* p0 = (const float4*)(XWf + (size_t)s0*FH + li*16);
    const float4* p1 = (const float4*)(XWf + (size_t)s1*FH + li*16);
    float4 a0 = p0[0], a1 = p0[1], a2 = p0[2], a3 = p0[3];
    float4 c0 = p1[0], c1 = p1[1], c2 = p1[2], c3 = p1[3];
    acc[0]+=a0.x+c0.x; acc[1]+=a0.y+c0.y; acc[2]+=a0.z+c0.z; acc[3]+=a0.w+c0.w;
    acc[4]+=a1.x+c1.x; acc[5]+=a1.y+c1.y; acc[6]+=a1.z+c1.z; acc[7]+=a1.w+c1.w;
    acc[8]+=a2.x+c2.x; acc[9]+=a2.y+c2.y; acc[10]+=a2.z+c2.z; acc[11]+=a2.w+c2.w;
    acc[12]+=a3.x+c3.x; acc[13]+=a3.y+c3.y; acc[14]+=a3.z+c3.z; acc[15]+=a3.w+c3.w;
  }
  if(j < end){
    int s0 = srcs[j];
    const float4* p0 = (const float4*)(XWf + (size_t)s0*FH + li*16);
    float4 a0 = p0[0], a1 = p0[1], a2 = p0[2], a3 = p0[3];
    acc[0]+=a0.x; acc[1]+=a0.y; acc[2]+=a0.z; acc[3]+=a0.w;
    acc[4]+=a1.x; acc[5]+=a1.y; acc[6]+=a1.z; acc[7]+=a1.w;
    acc[8]+=a2.x; acc[9]+=a2.y; acc[10]+=a2.z; acc[11]+=a2.w;
    acc[12]+=a3.x; acc[13]+=a3.y; acc[14]+=a3.z; acc[15]+=a3.w;
  }
  #pragma unroll
  for(int k=0;k<16;k++){
    acc[k] += __shfl_xor(acc[k], 8);
    acc[k] += __shfl_xor(acc[k], 16);
    acc[k] += __shfl_xor(acc[k], 32);
  }
  // self + epilogue
  const float4* sp = (const float4*)(XWf + (size_t)d*FH + li*16);
  float4 s0 = sp[0], s1 = sp[1], s2 = sp[2], s3 = sp[3];
  float dd = dinv[d];
  float slf[16] = {s0.x,s0.y,s0.z,s0.w, s1.x,s1.y,s1.z,s1.w,
                   s2.x,s2.y,s2.z,s2.w, s3.x,s3.y,s3.z,s3.w};
  float o[16];
  #pragma unroll
  for(int k=0;k<16;k++){
    float bb = b1[li*16 + k];
    o[k] = fmaxf((acc[k]+slf[k])*dd + bb, 0.f);
  }
  if(g == 0){
    uint4 w0, w1;
    w0.x = pk(o[0],o[1]);  w0.y = pk(o[2],o[3]);  w0.z = pk(o[4],o[5]);  w0.w = pk(o[6],o[7]);
    w1.x = pk(o[8],o[9]);  w1.y = pk(o[10],o[11]); w1.z = pk(o[12],o[13]); w1.w = pk(o[14],o[15]);
    uint4* wp = (uint4*)(H1b + (size_t)d*FH + li*16);
    wp[0] = w0;
    wp[1] = w1;
  }
}

// ---------------- GEMM2 via MFMA: H2f[n,64] = (H1b @ W2) * dinv[row], fp32 out, cols>=40 zero ---
__global__ __launch_bounds__(256) void k_gemm2_mfma(const ushort* __restrict__ H1b,
                                                    const ushort* __restrict__ W2t,
                                                    const float* __restrict__ dinv,
                                                    float* __restrict__ H2f, int n){
  int t = threadIdx.x;
  int lane = t & 63;
  int wid = t >> 6;
  int l15 = lane & 15;
  int lk8 = (lane >> 4) * 8;
  int rowbase = blockIdx.x * 128 + wid * 32;

  int r0 = rowbase + l15;      if (r0 >= n) r0 = n-1;
  int r1 = rowbase + 16 + l15; if (r1 >= n) r1 = n-1;
  const ushort* a0p = H1b + (size_t)r0*FH + lk8;
  const ushort* a1p = H1b + (size_t)r1*FH + lk8;

  f32x4 acc[2][3];
  #pragma unroll
  for(int i=0;i<2;i++)
    #pragma unroll
    for(int j=0;j<3;j++) acc[i][j] = (f32x4){0.f,0.f,0.f,0.f};

  #pragma unroll
  for(int kc=0; kc<4; kc++){
    int k0 = kc*32;
    bf16x8 fa0 = *(const bf16x8*)(a0p + k0);
    bf16x8 fa1 = *(const bf16x8*)(a1p + k0);
    #pragma unroll
    for(int fj=0; fj<3; fj++){
      bf16x8 fb = *(const bf16x8*)(W2t + (size_t)(fj*16 + l15)*FH + k0 + lk8);
      acc[0][fj] = __builtin_amdgcn_mfma_f32_16x16x32_bf16(fa0, fb, acc[0][fj], 0, 0, 0);
      acc[1][fj] = __builtin_amdgcn_mfma_f32_16x16x32_bf16(fa1, fb, acc[1][fj], 0, 0, 0);
    }
  }

  int rbase = (lane >> 4) * 4;
  #pragma unroll
  for(int fi=0; fi<2; fi++){
    #pragma unroll
    for(int r=0; r<4; r++){
      int row = rowbase + fi*16 + rbase + r;
      if(row < n){
        float dd = dinv[row];
        #pragma unroll
        for(int fj=0; fj<3; fj++){
          int col = fj*16 + l15;
          H2f[(size_t)row*FP + col] = (col < FOUT) ? acc[fi][fj][r] * dd : 0.f;
        }
        H2f[(size_t)row*FP + 48 + l15] = 0.f;
      }
    }
  }
}

// ---------------- agg2 + bias + log_softmax: out[d] = lsm(dd*(sum H2f[s] + H2f[d]) + b2) ---
// wave per node; 8 groups x 8 lanes; fp32 gather (2 x float4 / lane), 2-edge unroll.
__global__ __launch_bounds__(256) void k_agg2_sm(const float* __restrict__ H2f, const int* __restrict__ rp,
                                                 const int* __restrict__ srcs, const float* __restrict__ dinv,
                                                 const float* __restrict__ b2, float* __restrict__ out, int n){
  int d = blockIdx.x*4 + (threadIdx.x >> 6);
  if(d >= n) return;
  int lane = threadIdx.x & 63;
  int g = lane >> 3, li = lane & 7;
  float acc[8];
  #pragma unroll
  for(int k=0;k<8;k++) acc[k]=0.f;
  int beg = rp[d], end = rp[d+1];
  int j = beg + g;
  for(; j + 8 < end; j += 16){
    int s0 = srcs[j];
    int s1 = srcs[j+8];
    const float4* p0 = (const float4*)(H2f + (size_t)s0*FP + li*8);
    const float4* p1 = (const float4*)(H2f + (size_t)s1*FP + li*8);
    float4 v0 = p0[0], v1 = p0[1];
    float4 u0 = p1[0], u1 = p1[1];
    acc[0]+=v0.x+u0.x; acc[1]+=v0.y+u0.y; acc[2]+=v0.z+u0.z; acc[3]+=v0.w+u0.w;
    acc[4]+=v1.x+u1.x; acc[5]+=v1.y+u1.y; acc[6]+=v1.z+u1.z; acc[7]+=v1.w+u1.w;
  }
  if(j < end){
    int s0 = srcs[j];
    const float4* p0 = (const float4*)(H2f + (size_t)s0*FP + li*8);
    float4 v0 = p0[0], v1 = p0[1];
    acc[0]+=v0.x; acc[1]+=v0.y; acc[2]+=v0.z; acc[3]+=v0.w;
    acc[4]+=v1.x; acc[5]+=v1.y; acc[6]+=v1.z; acc[7]+=v1.w;
  }
  #pragma unroll
  for(int k=0;k<8;k++){
    acc[k] += __shfl_xor(acc[k], 8);
    acc[k] += __shfl_xor(acc[k], 16);
    acc[k] += __shfl_xor(acc[k], 32);
  }
  const float4* sp = (const float4*)(H2f + (size_t)d*FP + li*8);
  float4 s0 = sp[0], s1 = sp[1];
  acc[0]+=s0.x; acc[1]+=s0.y; acc[2]+=s0.z; acc[3]+=s0.w;
  acc[4]+=s1.x; acc[5]+=s1.y; acc[6]+=s1.z; acc[7]+=s1.w;
  float dd = dinv[d];
  float val[8];
  #pragma unroll
  for(int k=0;k<8;k++){
    int col = li*8 + k;
    float bv = (col < FOUT) ? b2[col] : 0.f;
    val[k] = (col < FOUT) ? (acc[k]*dd + bv) : -3.402823466e38f;
  }
  float m = val[0];
  #pragma unroll
  for(int k=1;k<8;k++) m = fmaxf(m, val[k]);
  #pragma unroll
  for(int off=1; off<8; off<<=1) m = fmaxf(m, __shfl_xor(m, off));
  float ssum = 0.f;
  #pragma unroll
  for(int k=0;k<8;k++){
    int col = li*8 + k;
    ssum += (col < FOUT) ? expf(val[k] - m) : 0.f;
  }
  #pragma unroll
  for(int off=1; off<8; off<<=1) ssum += __shfl_xor(ssum, off);
  float lse = m + logf(ssum);
  if(g == 0 && li < 5){
    float4 o0 = {val[0]-lse, val[1]-lse, val[2]-lse, val[3]-lse};
    float4 o1 = {val[4]-lse, val[5]-lse, val[6]-lse, val[7]-lse};
    float* op = out + (size_t)d*FOUT + li*8;
    *(float4*)op = o0;
    *(float4*)(op+4) = o1;
  }
}

// ---------------- launch ----------------

extern "C" void kernel_launch(void* const* d_in, const int* in_sizes, int n_in,
                              void* d_out, int out_size, void* d_ws, size_t ws_size,
                              hipStream_t stream){
  const float* X  = (const float*)d_in[0];
  const int*   ei = (const int*)d_in[1];
  const float* W1 = (const float*)d_in[2];
  const float* b1 = (const float*)d_in[3];
  const float* W2 = (const float*)d_in[4];
  const float* b2 = (const float*)d_in[5];
  float* out = (float*)d_out;

  int n = in_sizes[0] / FIN;      // 100000
  int e = in_sizes[1] / 2;        // 1600000
  const int* src = ei;
  const int* dst = ei + e;

  // workspace layout
  float* XWf   = (float*)d_ws;                       // n*128 f32 (dinv-scaled XW)
  float* H2f   = XWf + (size_t)n*FH;                 // n*64  f32 (dinv-scaled, padded)
  ushort* H1b  = (ushort*)(H2f + (size_t)n*FP);      // n*128 bf16
  ushort* W1t  = H1b + (size_t)n*FH;                 // 128*512
  ushort* W2t  = W1t + (size_t)FH*FIN;               // 48*128
  float* dinv  = (float*)(W2t + 48*FH);              // n
  int* cnt     = (int*)(dinv + n);                   // n
  int* cursor  = cnt + n;                            // n
  int* rp      = cursor + n;                         // n+1
  int* srcs    = rp + (n+1) + 3;                     // e
  int* aux     = srcs + e;                           // 256

  int nchunks = (n + 1023) / 1024;

  hipLaunchKernelGGL(k_init, dim3((2*n+255)/256), dim3(256), 0, stream, cnt, 2*n, W1, W2, W1t, W2t);
  hipLaunchKernelGGL(k_count, dim3((e+255)/256), dim3(256), 0, stream, dst, e, cnt);
  hipLaunchKernelGGL(k_scan_a, dim3(nchunks), dim3(256), 0, stream, cnt, n, rp, aux);
  hipLaunchKernelGGL(k_scan_b, dim3(1), dim3(256), 0, stream, aux, nchunks);
  hipLaunchKernelGGL(k_scan_c, dim3((n+255)/256), dim3(256), 0, stream, rp, aux, cnt, dinv, n);
  hipLaunchKernelGGL(k_fill, dim3((e+255)/256), dim3(256), 0, stream, src, dst, e, rp, cursor, srcs);

  hipLaunchKernelGGL(k_gemm1_mfma, dim3((n+63)/64), dim3(256), 0, stream, X, W1t, dinv, XWf, n);
  hipLaunchKernelGGL(k_agg1, dim3((n+3)/4), dim3(256), 0, stream, XWf, rp, srcs, dinv, b1, H1b, n);
  hipLaunchKernelGGL(k_gemm2_mfma, dim3((n+127)/128), dim3(256), 0, stream, H1b, W2t, dinv, H2f, n);
  hipLaunchKernelGGL(k_agg2_sm, dim3((n+3)/4), dim3(256), 0, stream, H2f, rp, srcs, dinv, b2, out, n);
}

// Round 8
// 378.175 us; speedup vs baseline: 1.1795x; 1.1795x over previous
//
#include <hip/hip_runtime.h>
#include <math.h>

#define FIN 512
#define FH 128
#define FOUT 40
#define FP 64   // padded H2 width

typedef __attribute__((ext_vector_type(8))) short bf16x8;
typedef __attribute__((ext_vector_type(4))) float f32x4;
typedef __attribute__((ext_vector_type(2))) float f32x2;

__device__ inline ushort f2bf(float f){
  union { float f; uint32_t u; } v; v.f = f;
  uint32_t u = v.u;
  uint32_t r = (u + 0x7FFF + ((u >> 16) & 1)) >> 16;
  return (ushort)r;
}
__device__ inline float bflo(uint32_t v){ union { uint32_t u; float f; } x; x.u = v << 16; return x.f; }
__device__ inline float bfhi(uint32_t v){ union { uint32_t u; float f; } x; x.u = v & 0xFFFF0000u; return x.f; }
__device__ inline uint32_t pk(float a, float b){ return (uint32_t)f2bf(a) | ((uint32_t)f2bf(b) << 16); }

// unpack one dword (2 bf16) into a packed f32 pair
__device__ inline f32x2 bfup(uint32_t v){
  union { uint32_t u; float f; } lo, hi;
  lo.u = v << 16; hi.u = v & 0xFFFF0000u;
  f32x2 r; r[0] = lo.f; r[1] = hi.f; return r;
}
// packed f32 add (v_pk_add_f32, one VALU op for 2 floats)
__device__ inline f32x2 pkadd(f32x2 a, f32x2 b){
  f32x2 r;
  asm("v_pk_add_f32 %0, %1, %2" : "=v"(r) : "v"(a), "v"(b));
  return r;
}

// ---------------- CSR build ----------------

__global__ void k_init(int* __restrict__ p, int n2,
                       const float* __restrict__ W1, const float* __restrict__ W2,
                       ushort* __restrict__ W1t, ushort* __restrict__ W2t){
  int i = blockIdx.x*256 + threadIdx.x;
  if(i<n2) p[i]=0;
  if(i < FIN*FH){
    int k = i / FH, c = i % FH;
    W1t[(size_t)c*FIN + k] = f2bf(W1[i]);
  }
  if(i < 48*FH){
    int c = i / FH, k = i % FH;
    W2t[i] = (c < FOUT) ? f2bf(W2[(size_t)k*FOUT + c]) : (ushort)0;
  }
}

__global__ void k_count(const int* __restrict__ dst, int e, int* __restrict__ cnt){
  int i = blockIdx.x*256 + threadIdx.x;
  if(i<e) atomicAdd(&cnt[dst[i]],1);
}

__global__ void k_scan_a(const int* __restrict__ cnt, int n, int* __restrict__ rp, int* __restrict__ aux){
  __shared__ int sh[256];
  int t = threadIdx.x;
  int base = blockIdx.x*1024;
  int v[4]; int s = 0;
  #pragma unroll
  for(int j=0;j<4;j++){ int idx = base + t*4 + j; int x = (idx<n)?cnt[idx]:0; v[j]=x; s+=x; }
  sh[t]=s; __syncthreads();
  for(int off=1; off<256; off<<=1){
    int x = (t>=off)? sh[t-off]:0; __syncthreads();
    sh[t]+=x; __syncthreads();
  }
  int run = (t>0)? sh[t-1]:0;
  #pragma unroll
  for(int j=0;j<4;j++){ run += v[j]; int idx = base + t*4 + j; if(idx<n) rp[idx+1]=run; }
  if(t==255) aux[blockIdx.x]=sh[255];
}

__global__ void k_scan_b(int* __restrict__ aux, int nchunks){
  __shared__ int sh[256];
  int t = threadIdx.x;
  sh[t] = (t<nchunks)? aux[t] : 0;
  __syncthreads();
  for(int off=1; off<256; off<<=1){
    int x = (t>=off)? sh[t-off]:0; __syncthreads();
    sh[t]+=x; __syncthreads();
  }
  if(t<nchunks) aux[t] = (t>0)? sh[t-1] : 0;
}

__global__ void k_scan_c(int* __restrict__ rp, const int* __restrict__ aux,
                         const int* __restrict__ cnt, float* __restrict__ dinv, int n){
  int i = blockIdx.x*256 + threadIdx.x;
  if(i<n){
    rp[i+1] += aux[i>>10];
    dinv[i] = rsqrtf((float)(cnt[i]+1));
  }
  if(i==0) rp[0] = 0;
}

__global__ void k_fill(const int* __restrict__ src, const int* __restrict__ dst, int e,
                       const int* __restrict__ rp, int* __restrict__ cursor, int* __restrict__ srcs){
  int i = blockIdx.x*256 + threadIdx.x;
  if(i<e){
    int d = dst[i];
    int p = rp[d] + atomicAdd(&cursor[d],1);
    srcs[p] = src[i];
  }
}

// ---------------- GEMM1 via MFMA, W1 staged in LDS (two 64KB K-halves) ----------------
// 512 thr = 8 waves x 32 rows = 256 rows/block; B frags from swizzled LDS, A streamed.
__global__ __launch_bounds__(512, 2) void k_gemm1_mfma(const float* __restrict__ X,
                                                       const ushort* __restrict__ W1t,
                                                       const float* __restrict__ dinv,
                                                       ushort* __restrict__ XWs, int n){
  __shared__ ushort Ws[FH * 256];   // 64 KB: [128 cols][256 k] bf16, XOR-swizzled
  int t = threadIdx.x;
  int lane = t & 63;
  int wid = t >> 6;
  int l15 = lane & 15;
  int lk8 = (lane >> 4) * 8;
  int rowbase = blockIdx.x * 256 + wid * 32;

  int r0 = rowbase + l15;      if (r0 >= n) r0 = n-1;
  int r1 = rowbase + 16 + l15; if (r1 >= n) r1 = n-1;
  const float* a0p = X + (size_t)r0*FIN;
  const float* a1p = X + (size_t)r1*FIN;

  f32x4 acc[2][8];
  #pragma unroll
  for(int i=0;i<2;i++)
    #pragma unroll
    for(int j=0;j<8;j++) acc[i][j] = (f32x4){0.f,0.f,0.f,0.f};

  char* WsB = (char*)Ws;

  #pragma unroll
  for(int half=0; half<2; half++){
    if(half) __syncthreads();
    #pragma unroll
    for(int it=0; it<8; it++){
      int c = it*512 + t;
      int col = c >> 5, kslot = c & 31;
      uint4 v = *(const uint4*)(W1t + (size_t)col*FIN + half*256 + kslot*8);
      int dstb = col*512 + ((kslot*16) ^ ((col & 7) << 4));
      *(uint4*)(WsB + dstb) = v;
    }
    __syncthreads();

    for(int kc=0; kc<8; kc++){
      int kl = kc*32 + lk8;
      int kg = half*256 + kl;
      float4 a0a = *(const float4*)(a0p + kg);
      float4 a0b = *(const float4*)(a0p + kg + 4);
      float4 a1a = *(const float4*)(a1p + kg);
      float4 a1b = *(const float4*)(a1p + kg + 4);
      bf16x8 fa0, fa1;
      fa0[0]=(short)f2bf(a0a.x); fa0[1]=(short)f2bf(a0a.y); fa0[2]=(short)f2bf(a0a.z); fa0[3]=(short)f2bf(a0a.w);
      fa0[4]=(short)f2bf(a0b.x); fa0[5]=(short)f2bf(a0b.y); fa0[6]=(short)f2bf(a0b.z); fa0[7]=(short)f2bf(a0b.w);
      fa1[0]=(short)f2bf(a1a.x); fa1[1]=(short)f2bf(a1a.y); fa1[2]=(short)f2bf(a1a.z); fa1[3]=(short)f2bf(a1a.w);
      fa1[4]=(short)f2bf(a1b.x); fa1[5]=(short)f2bf(a1b.y); fa1[6]=(short)f2bf(a1b.z); fa1[7]=(short)f2bf(a1b.w);

      #pragma unroll
      for(int fj=0; fj<8; fj++){
        int col = fj*16 + l15;
        int srcb = col*512 + ((kl*2) ^ ((col & 7) << 4));
        bf16x8 fb = *(const bf16x8*)(WsB + srcb);
        acc[0][fj] = __builtin_amdgcn_mfma_f32_16x16x32_bf16(fa0, fb, acc[0][fj], 0, 0, 0);
        acc[1][fj] = __builtin_amdgcn_mfma_f32_16x16x32_bf16(fa1, fb, acc[1][fj], 0, 0, 0);
      }
    }
  }

  int rbase = (lane >> 4) * 4;
  #pragma unroll
  for(int fi=0; fi<2; fi++){
    #pragma unroll
    for(int r=0; r<4; r++){
      int row = rowbase + fi*16 + rbase + r;
      if(row < n){
        float dd = dinv[row];
        #pragma unroll
        for(int fj=0; fj<8; fj++){
          XWs[(size_t)row*FH + fj*16 + l15] = f2bf(acc[fi][fj][r] * dd);
        }
      }
    }
  }
}

// ---------------- agg1: H1b = relu(dd*(sum_s XWs[s] + XWs[d]) + b1), bf16 out ----------------
// wave per node; 8 groups x 8 lanes; bf16 gather (2 x uint4 / lane), 2-edge unroll,
// srcs prefetch, packed-f32 accumulate.
__global__ __launch_bounds__(256) void k_agg1(const ushort* __restrict__ XWs, const int* __restrict__ rp,
                                              const int* __restrict__ srcs, const float* __restrict__ dinv,
                                              const float* __restrict__ b1, ushort* __restrict__ H1b, int n){
  int d = blockIdx.x*4 + (threadIdx.x >> 6);
  if(d >= n) return;
  int lane = threadIdx.x & 63;
  int g = lane >> 3, li = lane & 7;
  f32x2 acc[8];
  #pragma unroll
  for(int k=0;k<8;k++) acc[k] = (f32x2){0.f,0.f};
  int beg = rp[d], end = rp[d+1];
  int j = beg + g;
  bool h0 = j < end, h1 = j + 8 < end;
  int s0 = 0, s1 = 0;
  if(h0) s0 = srcs[j];
  if(h1) s1 = srcs[j+8];
  while(h1){
    int nj = j + 16;
    bool nh0 = nj < end, nh1 = nj + 8 < end;
    int ns0 = 0, ns1 = 0;
    if(nh0) ns0 = srcs[nj];
    if(nh1) ns1 = srcs[nj+8];
    const uint4* p0 = (const uint4*)(XWs + (size_t)s0*FH + li*16);
    const uint4* p1 = (const uint4*)(XWs + (size_t)s1*FH + li*16);
    uint4 a0 = p0[0], a1 = p0[1];
    uint4 c0 = p1[0], c1 = p1[1];
    acc[0] = pkadd(acc[0], pkadd(bfup(a0.x), bfup(c0.x)));
    acc[1] = pkadd(acc[1], pkadd(bfup(a0.y), bfup(c0.y)));
    acc[2] = pkadd(acc[2], pkadd(bfup(a0.z), bfup(c0.z)));
    acc[3] = pkadd(acc[3], pkadd(bfup(a0.w), bfup(c0.w)));
    acc[4] = pkadd(acc[4], pkadd(bfup(a1.x), bfup(c1.x)));
    acc[5] = pkadd(acc[5], pkadd(bfup(a1.y), bfup(c1.y)));
    acc[6] = pkadd(acc[6], pkadd(bfup(a1.z), bfup(c1.z)));
    acc[7] = pkadd(acc[7], pkadd(bfup(a1.w), bfup(c1.w)));
    j = nj; s0 = ns0; s1 = ns1; h0 = nh0; h1 = nh1;
  }
  if(h0){
    const uint4* p0 = (const uint4*)(XWs + (size_t)s0*FH + li*16);
    uint4 a0 = p0[0], a1 = p0[1];
    acc[0] = pkadd(acc[0], bfup(a0.x));
    acc[1] = pkadd(acc[1], bfup(a0.y));
    acc[2] = pkadd(acc[2], bfup(a0.z));
    acc[3] = pkadd(acc[3], bfup(a0.w));
    acc[4] = pkadd(acc[4], bfup(a1.x));
    acc[5] = pkadd(acc[5], bfup(a1.y));
    acc[6] = pkadd(acc[6], bfup(a1.z));
    acc[7] = pkadd(acc[7], bfup(a1.w));
  }
  #pragma unroll
  for(int k=0;k<8;k++){
    #pragma unroll
    for(int c=0;c<2;c++){
      acc[k][c] += __shfl_xor(acc[k][c], 8);
      acc[k][c] += __shfl_xor(acc[k][c], 16);
      acc[k][c] += __shfl_xor(acc[k][c], 32);
    }
  }
  // self + epilogue
  const uint4* sp = (const uint4*)(XWs + (size_t)d*FH + li*16);
  uint4 s0v = sp[0], s1v = sp[1];
  float dd = dinv[d];
  uint32_t sd[8] = {s0v.x,s0v.y,s0v.z,s0v.w, s1v.x,s1v.y,s1v.z,s1v.w};
  float o[16];
  #pragma unroll
  for(int k=0;k<8;k++){
    f32x2 sv = bfup(sd[k]);
    float b0 = b1[li*16 + k*2];
    float b1v = b1[li*16 + k*2 + 1];
    o[k*2]   = fmaxf((acc[k][0]+sv[0])*dd + b0, 0.f);
    o[k*2+1] = fmaxf((acc[k][1]+sv[1])*dd + b1v, 0.f);
  }
  if(g == 0){
    uint4 w0, w1;
    w0.x = pk(o[0],o[1]);  w0.y = pk(o[2],o[3]);  w0.z = pk(o[4],o[5]);  w0.w = pk(o[6],o[7]);
    w1.x = pk(o[8],o[9]);  w1.y = pk(o[10],o[11]); w1.z = pk(o[12],o[13]); w1.w = pk(o[14],o[15]);
    uint4* wp = (uint4*)(H1b + (size_t)d*FH + li*16);
    wp[0] = w0;
    wp[1] = w1;
  }
}

// ---------------- GEMM2 via MFMA: H2s[n,64] = (H1b @ W2) * dinv[row], bf16, cols>=40 zero ---
__global__ __launch_bounds__(256) void k_gemm2_mfma(const ushort* __restrict__ H1b,
                                                    const ushort* __restrict__ W2t,
                                                    const float* __restrict__ dinv,
                                                    ushort* __restrict__ H2s, int n){
  int t = threadIdx.x;
  int lane = t & 63;
  int wid = t >> 6;
  int l15 = lane & 15;
  int lk8 = (lane >> 4) * 8;
  int rowbase = blockIdx.x * 128 + wid * 32;

  int r0 = rowbase + l15;      if (r0 >= n) r0 = n-1;
  int r1 = rowbase + 16 + l15; if (r1 >= n) r1 = n-1;
  const ushort* a0p = H1b + (size_t)r0*FH + lk8;
  const ushort* a1p = H1b + (size_t)r1*FH + lk8;

  f32x4 acc[2][3];
  #pragma unroll
  for(int i=0;i<2;i++)
    #pragma unroll
    for(int j=0;j<3;j++) acc[i][j] = (f32x4){0.f,0.f,0.f,0.f};

  #pragma unroll
  for(int kc=0; kc<4; kc++){
    int k0 = kc*32;
    bf16x8 fa0 = *(const bf16x8*)(a0p + k0);
    bf16x8 fa1 = *(const bf16x8*)(a1p + k0);
    #pragma unroll
    for(int fj=0; fj<3; fj++){
      bf16x8 fb = *(const bf16x8*)(W2t + (size_t)(fj*16 + l15)*FH + k0 + lk8);
      acc[0][fj] = __builtin_amdgcn_mfma_f32_16x16x32_bf16(fa0, fb, acc[0][fj], 0, 0, 0);
      acc[1][fj] = __builtin_amdgcn_mfma_f32_16x16x32_bf16(fa1, fb, acc[1][fj], 0, 0, 0);
    }
  }

  int rbase = (lane >> 4) * 4;
  #pragma unroll
  for(int fi=0; fi<2; fi++){
    #pragma unroll
    for(int r=0; r<4; r++){
      int row = rowbase + fi*16 + rbase + r;
      if(row < n){
        float dd = dinv[row];
        #pragma unroll
        for(int fj=0; fj<3; fj++){
          int col = fj*16 + l15;
          H2s[(size_t)row*FP + col] = (col < FOUT) ? f2bf(acc[fi][fj][r] * dd) : (ushort)0;
        }
        H2s[(size_t)row*FP + 48 + l15] = 0;
      }
    }
  }
}

// ---------------- agg2 + bias + log_softmax ----------------
// wave per node; 8 groups x 8 lanes; bf16 gather (1 uint4/lane), 2-edge unroll,
// srcs prefetch, packed-f32 accumulate.
__global__ __launch_bounds__(256) void k_agg2_sm(const ushort* __restrict__ H2s, const int* __restrict__ rp,
                                                 const int* __restrict__ srcs, const float* __restrict__ dinv,
                                                 const float* __restrict__ b2, float* __restrict__ out, int n){
  int d = blockIdx.x*4 + (threadIdx.x >> 6);
  if(d >= n) return;
  int lane = threadIdx.x & 63;
  int g = lane >> 3, li = lane & 7;
  f32x2 acc[4];
  #pragma unroll
  for(int k=0;k<4;k++) acc[k] = (f32x2){0.f,0.f};
  int beg = rp[d], end = rp[d+1];
  int j = beg + g;
  bool h0 = j < end, h1 = j + 8 < end;
  int s0 = 0, s1 = 0;
  if(h0) s0 = srcs[j];
  if(h1) s1 = srcs[j+8];
  while(h1){
    int nj = j + 16;
    bool nh0 = nj < end, nh1 = nj + 8 < end;
    int ns0 = 0, ns1 = 0;
    if(nh0) ns0 = srcs[nj];
    if(nh1) ns1 = srcs[nj+8];
    uint4 v = *(const uint4*)(H2s + (size_t)s0*FP + li*8);
    uint4 u = *(const uint4*)(H2s + (size_t)s1*FP + li*8);
    acc[0] = pkadd(acc[0], pkadd(bfup(v.x), bfup(u.x)));
    acc[1] = pkadd(acc[1], pkadd(bfup(v.y), bfup(u.y)));
    acc[2] = pkadd(acc[2], pkadd(bfup(v.z), bfup(u.z)));
    acc[3] = pkadd(acc[3], pkadd(bfup(v.w), bfup(u.w)));
    j = nj; s0 = ns0; s1 = ns1; h0 = nh0; h1 = nh1;
  }
  if(h0){
    uint4 v = *(const uint4*)(H2s + (size_t)s0*FP + li*8);
    acc[0] = pkadd(acc[0], bfup(v.x));
    acc[1] = pkadd(acc[1], bfup(v.y));
    acc[2] = pkadd(acc[2], bfup(v.z));
    acc[3] = pkadd(acc[3], bfup(v.w));
  }
  #pragma unroll
  for(int k=0;k<4;k++){
    #pragma unroll
    for(int c=0;c<2;c++){
      acc[k][c] += __shfl_xor(acc[k][c], 8);
      acc[k][c] += __shfl_xor(acc[k][c], 16);
      acc[k][c] += __shfl_xor(acc[k][c], 32);
    }
  }
  uint4 sv = *(const uint4*)(H2s + (size_t)d*FP + li*8);
  uint32_t sd[4] = {sv.x, sv.y, sv.z, sv.w};
  float dd = dinv[d];
  float val[8];
  #pragma unroll
  for(int k=0;k<4;k++){
    f32x2 s2 = bfup(sd[k]);
    #pragma unroll
    for(int c=0;c<2;c++){
      int col = li*8 + k*2 + c;
      float bv = (col < FOUT) ? b2[col] : 0.f;
      val[k*2+c] = (col < FOUT) ? ((acc[k][c]+s2[c])*dd + bv) : -3.402823466e38f;
    }
  }
  float m = val[0];
  #pragma unroll
  for(int k=1;k<8;k++) m = fmaxf(m, val[k]);
  #pragma unroll
  for(int off=1; off<8; off<<=1) m = fmaxf(m, __shfl_xor(m, off));
  float ssum = 0.f;
  #pragma unroll
  for(int k=0;k<8;k++){
    int col = li*8 + k;
    ssum += (col < FOUT) ? expf(val[k] - m) : 0.f;
  }
  #pragma unroll
  for(int off=1; off<8; off<<=1) ssum += __shfl_xor(ssum, off);
  float lse = m + logf(ssum);
  if(g == 0 && li < 5){
    float4 o0 = {val[0]-lse, val[1]-lse, val[2]-lse, val[3]-lse};
    float4 o1 = {val[4]-lse, val[5]-lse, val[6]-lse, val[7]-lse};
    float* op = out + (size_t)d*FOUT + li*8;
    *(float4*)op = o0;
    *(float4*)(op+4) = o1;
  }
}

// ---------------- launch ----------------

extern "C" void kernel_launch(void* const* d_in, const int* in_sizes, int n_in,
                              void* d_out, int out_size, void* d_ws, size_t ws_size,
                              hipStream_t stream){
  const float* X  = (const float*)d_in[0];
  const int*   ei = (const int*)d_in[1];
  const float* W1 = (const float*)d_in[2];
  const float* b1 = (const float*)d_in[3];
  const float* W2 = (const float*)d_in[4];
  const float* b2 = (const float*)d_in[5];
  float* out = (float*)d_out;

  int n = in_sizes[0] / FIN;      // 100000
  int e = in_sizes[1] / 2;        // 1600000
  const int* src = ei;
  const int* dst = ei + e;

  // workspace layout
  ushort* XWs = (ushort*)d_ws;                       // n*128 bf16 (dinv-scaled XW)
  ushort* H1b = XWs + (size_t)n*FH;                  // n*128 bf16
  ushort* H2s = H1b + (size_t)n*FH;                  // n*64  bf16 (dinv-scaled, padded)
  ushort* W1t = H2s + (size_t)n*FP;                  // 128*512
  ushort* W2t = W1t + (size_t)FH*FIN;                // 48*128
  float* dinv = (float*)(W2t + 48*FH);               // n
  int* cnt    = (int*)(dinv + n);                    // n
  int* cursor = cnt + n;                             // n
  int* rp     = cursor + n;                          // n+1
  int* srcs   = rp + (n+1) + 3;                      // e
  int* aux    = srcs + e;                            // 256

  int nchunks = (n + 1023) / 1024;

  hipLaunchKernelGGL(k_init, dim3((2*n+255)/256), dim3(256), 0, stream, cnt, 2*n, W1, W2, W1t, W2t);
  hipLaunchKernelGGL(k_count, dim3((e+255)/256), dim3(256), 0, stream, dst, e, cnt);
  hipLaunchKernelGGL(k_scan_a, dim3(nchunks), dim3(256), 0, stream, cnt, n, rp, aux);
  hipLaunchKernelGGL(k_scan_b, dim3(1), dim3(256), 0, stream, aux, nchunks);
  hipLaunchKernelGGL(k_scan_c, dim3((n+255)/256), dim3(256), 0, stream, rp, aux, cnt, dinv, n);
  hipLaunchKernelGGL(k_fill, dim3((e+255)/256), dim3(256), 0, stream, src, dst, e, rp, cursor, srcs);

  hipLaunchKernelGGL(k_gemm1_mfma, dim3((n+255)/256), dim3(512), 0, stream, X, W1t, dinv, XWs, n);
  hipLaunchKernelGGL(k_agg1, dim3((n+3)/4), dim3(256), 0, stream, XWs, rp, srcs, dinv, b1, H1b, n);
  hipLaunchKernelGGL(k_gemm2_mfma, dim3((n+127)/128), dim3(256), 0, stream, H1b, W2t, dinv, H2s, n);
  hipLaunchKernelGGL(k_agg2_sm, dim3((n+3)/4), dim3(256), 0, stream, H2s, rp, srcs, dinv, b2, out, n);
}

// Round 9
// 369.737 us; speedup vs baseline: 1.2064x; 1.0228x over previous
//
#include <hip/hip_runtime.h>
#include <math.h>

#define FIN 512
#define FH 128
#define FOUT 40
#define FP 64   // padded H2 width

typedef __attribute__((ext_vector_type(8))) short bf16x8;
typedef __attribute__((ext_vector_type(4))) float f32x4;
typedef __attribute__((ext_vector_type(2))) float f32x2;

__device__ inline ushort f2bf(float f){
  union { float f; uint32_t u; } v; v.f = f;
  uint32_t u = v.u;
  uint32_t r = (u + 0x7FFF + ((u >> 16) & 1)) >> 16;
  return (ushort)r;
}
// packed f32->bf16x2 (RNE), one VALU op
__device__ inline uint32_t cvtpk(float a, float b){
  uint32_t r;
  asm("v_cvt_pk_bf16_f32 %0, %1, %2" : "=v"(r) : "v"(a), "v"(b));
  return r;
}
// unpack one dword (2 bf16) into a packed f32 pair
__device__ inline f32x2 bfup(uint32_t v){
  union { uint32_t u; float f; } lo, hi;
  lo.u = v << 16; hi.u = v & 0xFFFF0000u;
  f32x2 r; r[0] = lo.f; r[1] = hi.f; return r;
}
// packed f32 add (v_pk_add_f32, one VALU op for 2 floats)
__device__ inline f32x2 pkadd(f32x2 a, f32x2 b){
  f32x2 r;
  asm("v_pk_add_f32 %0, %1, %2" : "=v"(r) : "v"(a), "v"(b));
  return r;
}

// ---------------- CSR build ----------------

__global__ void k_init(int* __restrict__ p, int n2,
                       const float* __restrict__ W1, const float* __restrict__ W2,
                       ushort* __restrict__ W1t, ushort* __restrict__ W2t){
  int i = blockIdx.x*256 + threadIdx.x;
  if(i<n2) p[i]=0;
  if(i < FIN*FH){
    int k = i / FH, c = i % FH;
    W1t[(size_t)c*FIN + k] = f2bf(W1[i]);
  }
  if(i < 48*FH){
    int c = i / FH, k = i % FH;
    W2t[i] = (c < FOUT) ? f2bf(W2[(size_t)k*FOUT + c]) : (ushort)0;
  }
}

__global__ void k_count(const int* __restrict__ dst, int e, int* __restrict__ cnt){
  int i = blockIdx.x*256 + threadIdx.x;
  if(i<e) atomicAdd(&cnt[dst[i]],1);
}

__global__ void k_scan_a(const int* __restrict__ cnt, int n, int* __restrict__ rp, int* __restrict__ aux){
  __shared__ int sh[256];
  int t = threadIdx.x;
  int base = blockIdx.x*1024;
  int v[4]; int s = 0;
  #pragma unroll
  for(int j=0;j<4;j++){ int idx = base + t*4 + j; int x = (idx<n)?cnt[idx]:0; v[j]=x; s+=x; }
  sh[t]=s; __syncthreads();
  for(int off=1; off<256; off<<=1){
    int x = (t>=off)? sh[t-off]:0; __syncthreads();
    sh[t]+=x; __syncthreads();
  }
  int run = (t>0)? sh[t-1]:0;
  #pragma unroll
  for(int j=0;j<4;j++){ run += v[j]; int idx = base + t*4 + j; if(idx<n) rp[idx+1]=run; }
  if(t==255) aux[blockIdx.x]=sh[255];
}

__global__ void k_scan_b(int* __restrict__ aux, int nchunks){
  __shared__ int sh[256];
  int t = threadIdx.x;
  sh[t] = (t<nchunks)? aux[t] : 0;
  __syncthreads();
  for(int off=1; off<256; off<<=1){
    int x = (t>=off)? sh[t-off]:0; __syncthreads();
    sh[t]+=x; __syncthreads();
  }
  if(t<nchunks) aux[t] = (t>0)? sh[t-1] : 0;
}

__global__ void k_scan_c(int* __restrict__ rp, const int* __restrict__ aux,
                         const int* __restrict__ cnt, float* __restrict__ dinv, int n){
  int i = blockIdx.x*256 + threadIdx.x;
  if(i<n){
    rp[i+1] += aux[i>>10];
    dinv[i] = rsqrtf((float)(cnt[i]+1));
  }
  if(i==0) rp[0] = 0;
}

__global__ void k_fill(const int* __restrict__ src, const int* __restrict__ dst, int e,
                       const int* __restrict__ rp, int* __restrict__ cursor, int* __restrict__ srcs){
  int i = blockIdx.x*256 + threadIdx.x;
  if(i<e){
    int d = dst[i];
    int p = rp[d] + atomicAdd(&cursor[d],1);
    srcs[p] = src[i];
  }
}

// ---------------- GEMM1 via MFMA, W1 staged in LDS (two 64KB K-halves) ----------------
// 512 thr = 8 waves x 32 rows = 256 rows/block; B frags from swizzled LDS, A streamed.
__global__ __launch_bounds__(512, 2) void k_gemm1_mfma(const float* __restrict__ X,
                                                       const ushort* __restrict__ W1t,
                                                       const float* __restrict__ dinv,
                                                       ushort* __restrict__ XWs, int n){
  __shared__ ushort Ws[FH * 256];   // 64 KB: [128 cols][256 k] bf16, XOR-swizzled
  int t = threadIdx.x;
  int lane = t & 63;
  int wid = t >> 6;
  int l15 = lane & 15;
  int lk8 = (lane >> 4) * 8;
  int rowbase = blockIdx.x * 256 + wid * 32;

  int r0 = rowbase + l15;      if (r0 >= n) r0 = n-1;
  int r1 = rowbase + 16 + l15; if (r1 >= n) r1 = n-1;
  const float* a0p = X + (size_t)r0*FIN;
  const float* a1p = X + (size_t)r1*FIN;

  f32x4 acc[2][8];
  #pragma unroll
  for(int i=0;i<2;i++)
    #pragma unroll
    for(int j=0;j<8;j++) acc[i][j] = (f32x4){0.f,0.f,0.f,0.f};

  char* WsB = (char*)Ws;

  #pragma unroll
  for(int half=0; half<2; half++){
    if(half) __syncthreads();
    #pragma unroll
    for(int it=0; it<8; it++){
      int c = it*512 + t;
      int col = c >> 5, kslot = c & 31;
      uint4 v = *(const uint4*)(W1t + (size_t)col*FIN + half*256 + kslot*8);
      int dstb = col*512 + ((kslot*16) ^ ((col & 7) << 4));
      *(uint4*)(WsB + dstb) = v;
    }
    __syncthreads();

    for(int kc=0; kc<8; kc++){
      int kl = kc*32 + lk8;
      int kg = half*256 + kl;
      float4 a0a = *(const float4*)(a0p + kg);
      float4 a0b = *(const float4*)(a0p + kg + 4);
      float4 a1a = *(const float4*)(a1p + kg);
      float4 a1b = *(const float4*)(a1p + kg + 4);
      uint4 fa0u, fa1u;
      fa0u.x = cvtpk(a0a.x, a0a.y); fa0u.y = cvtpk(a0a.z, a0a.w);
      fa0u.z = cvtpk(a0b.x, a0b.y); fa0u.w = cvtpk(a0b.z, a0b.w);
      fa1u.x = cvtpk(a1a.x, a1a.y); fa1u.y = cvtpk(a1a.z, a1a.w);
      fa1u.z = cvtpk(a1b.x, a1b.y); fa1u.w = cvtpk(a1b.z, a1b.w);
      bf16x8 fa0 = *(bf16x8*)&fa0u;
      bf16x8 fa1 = *(bf16x8*)&fa1u;

      #pragma unroll
      for(int fj=0; fj<8; fj++){
        int col = fj*16 + l15;
        int srcb = col*512 + ((kl*2) ^ ((col & 7) << 4));
        bf16x8 fb = *(const bf16x8*)(WsB + srcb);
        acc[0][fj] = __builtin_amdgcn_mfma_f32_16x16x32_bf16(fa0, fb, acc[0][fj], 0, 0, 0);
        acc[1][fj] = __builtin_amdgcn_mfma_f32_16x16x32_bf16(fa1, fb, acc[1][fj], 0, 0, 0);
      }
    }
  }

  int rbase = (lane >> 4) * 4;
  #pragma unroll
  for(int fi=0; fi<2; fi++){
    #pragma unroll
    for(int r=0; r<4; r++){
      int row = rowbase + fi*16 + rbase + r;
      if(row < n){
        float dd = dinv[row];
        #pragma unroll
        for(int fj=0; fj<8; fj++){
          XWs[(size_t)row*FH + fj*16 + l15] = f2bf(acc[fi][fj][r] * dd);
        }
      }
    }
  }
}

// ---------------- agg1: H1b = relu(dd*(sum_s XWs[s] + XWs[d]) + b1), bf16 out ----------------
// wave per node; 8 groups x 8 lanes; bf16 gather (2 x uint4 / lane), 2-edge unroll,
// srcs prefetch, packed-f32 accumulate.
__global__ __launch_bounds__(256) void k_agg1(const ushort* __restrict__ XWs, const int* __restrict__ rp,
                                              const int* __restrict__ srcs, const float* __restrict__ dinv,
                                              const float* __restrict__ b1, ushort* __restrict__ H1b, int n){
  int d = blockIdx.x*4 + (threadIdx.x >> 6);
  if(d >= n) return;
  int lane = threadIdx.x & 63;
  int g = lane >> 3, li = lane & 7;
  f32x2 acc[8];
  #pragma unroll
  for(int k=0;k<8;k++) acc[k] = (f32x2){0.f,0.f};
  int beg = rp[d], end = rp[d+1];
  int j = beg + g;
  bool h0 = j < end, h1 = j + 8 < end;
  int s0 = 0, s1 = 0;
  if(h0) s0 = srcs[j];
  if(h1) s1 = srcs[j+8];
  while(h1){
    int nj = j + 16;
    bool nh0 = nj < end, nh1 = nj + 8 < end;
    int ns0 = 0, ns1 = 0;
    if(nh0) ns0 = srcs[nj];
    if(nh1) ns1 = srcs[nj+8];
    const uint4* p0 = (const uint4*)(XWs + (size_t)s0*FH + li*16);
    const uint4* p1 = (const uint4*)(XWs + (size_t)s1*FH + li*16);
    uint4 a0 = p0[0], a1 = p0[1];
    uint4 c0 = p1[0], c1 = p1[1];
    acc[0] = pkadd(acc[0], pkadd(bfup(a0.x), bfup(c0.x)));
    acc[1] = pkadd(acc[1], pkadd(bfup(a0.y), bfup(c0.y)));
    acc[2] = pkadd(acc[2], pkadd(bfup(a0.z), bfup(c0.z)));
    acc[3] = pkadd(acc[3], pkadd(bfup(a0.w), bfup(c0.w)));
    acc[4] = pkadd(acc[4], pkadd(bfup(a1.x), bfup(c1.x)));
    acc[5] = pkadd(acc[5], pkadd(bfup(a1.y), bfup(c1.y)));
    acc[6] = pkadd(acc[6], pkadd(bfup(a1.z), bfup(c1.z)));
    acc[7] = pkadd(acc[7], pkadd(bfup(a1.w), bfup(c1.w)));
    j = nj; s0 = ns0; s1 = ns1; h0 = nh0; h1 = nh1;
  }
  if(h0){
    const uint4* p0 = (const uint4*)(XWs + (size_t)s0*FH + li*16);
    uint4 a0 = p0[0], a1 = p0[1];
    acc[0] = pkadd(acc[0], bfup(a0.x));
    acc[1] = pkadd(acc[1], bfup(a0.y));
    acc[2] = pkadd(acc[2], bfup(a0.z));
    acc[3] = pkadd(acc[3], bfup(a0.w));
    acc[4] = pkadd(acc[4], bfup(a1.x));
    acc[5] = pkadd(acc[5], bfup(a1.y));
    acc[6] = pkadd(acc[6], bfup(a1.z));
    acc[7] = pkadd(acc[7], bfup(a1.w));
  }
  #pragma unroll
  for(int k=0;k<8;k++){
    #pragma unroll
    for(int c=0;c<2;c++){
      acc[k][c] += __shfl_xor(acc[k][c], 8);
      acc[k][c] += __shfl_xor(acc[k][c], 16);
      acc[k][c] += __shfl_xor(acc[k][c], 32);
    }
  }
  // self + epilogue
  const uint4* sp = (const uint4*)(XWs + (size_t)d*FH + li*16);
  uint4 s0v = sp[0], s1v = sp[1];
  float dd = dinv[d];
  uint32_t sd[8] = {s0v.x,s0v.y,s0v.z,s0v.w, s1v.x,s1v.y,s1v.z,s1v.w};
  if(g == 0){
    uint32_t w[8];
    #pragma unroll
    for(int k=0;k<8;k++){
      f32x2 sv = bfup(sd[k]);
      float b0 = b1[li*16 + k*2];
      float b1v = b1[li*16 + k*2 + 1];
      float o0 = fmaxf((acc[k][0]+sv[0])*dd + b0, 0.f);
      float o1 = fmaxf((acc[k][1]+sv[1])*dd + b1v, 0.f);
      w[k] = cvtpk(o0, o1);
    }
    uint4 w0 = {w[0],w[1],w[2],w[3]};
    uint4 w1 = {w[4],w[5],w[6],w[7]};
    uint4* wp = (uint4*)(H1b + (size_t)d*FH + li*16);
    wp[0] = w0;
    wp[1] = w1;
  }
}

// ---------------- GEMM2 via MFMA: H2s[n,64] = (H1b @ W2) * dinv[row], bf16, cols>=40 zero ---
__global__ __launch_bounds__(256) void k_gemm2_mfma(const ushort* __restrict__ H1b,
                                                    const ushort* __restrict__ W2t,
                                                    const float* __restrict__ dinv,
                                                    ushort* __restrict__ H2s, int n){
  int t = threadIdx.x;
  int lane = t & 63;
  int wid = t >> 6;
  int l15 = lane & 15;
  int lk8 = (lane >> 4) * 8;
  int rowbase = blockIdx.x * 128 + wid * 32;

  int r0 = rowbase + l15;      if (r0 >= n) r0 = n-1;
  int r1 = rowbase + 16 + l15; if (r1 >= n) r1 = n-1;
  const ushort* a0p = H1b + (size_t)r0*FH + lk8;
  const ushort* a1p = H1b + (size_t)r1*FH + lk8;

  f32x4 acc[2][3];
  #pragma unroll
  for(int i=0;i<2;i++)
    #pragma unroll
    for(int j=0;j<3;j++) acc[i][j] = (f32x4){0.f,0.f,0.f,0.f};

  #pragma unroll
  for(int kc=0; kc<4; kc++){
    int k0 = kc*32;
    bf16x8 fa0 = *(const bf16x8*)(a0p + k0);
    bf16x8 fa1 = *(const bf16x8*)(a1p + k0);
    #pragma unroll
    for(int fj=0; fj<3; fj++){
      bf16x8 fb = *(const bf16x8*)(W2t + (size_t)(fj*16 + l15)*FH + k0 + lk8);
      acc[0][fj] = __builtin_amdgcn_mfma_f32_16x16x32_bf16(fa0, fb, acc[0][fj], 0, 0, 0);
      acc[1][fj] = __builtin_amdgcn_mfma_f32_16x16x32_bf16(fa1, fb, acc[1][fj], 0, 0, 0);
    }
  }

  int rbase = (lane >> 4) * 4;
  #pragma unroll
  for(int fi=0; fi<2; fi++){
    #pragma unroll
    for(int r=0; r<4; r++){
      int row = rowbase + fi*16 + rbase + r;
      if(row < n){
        float dd = dinv[row];
        #pragma unroll
        for(int fj=0; fj<3; fj++){
          int col = fj*16 + l15;
          H2s[(size_t)row*FP + col] = (col < FOUT) ? f2bf(acc[fi][fj][r] * dd) : (ushort)0;
        }
        H2s[(size_t)row*FP + 48 + l15] = 0;
      }
    }
  }
}

// ---------------- agg2 + bias + log_softmax ----------------
// wave per node; 8 groups x 8 lanes; bf16 gather (1 uint4/lane), 2-edge unroll,
// srcs prefetch, packed-f32 accumulate.
__global__ __launch_bounds__(256) void k_agg2_sm(const ushort* __restrict__ H2s, const int* __restrict__ rp,
                                                 const int* __restrict__ srcs, const float* __restrict__ dinv,
                                                 const float* __restrict__ b2, float* __restrict__ out, int n){
  int d = blockIdx.x*4 + (threadIdx.x >> 6);
  if(d >= n) return;
  int lane = threadIdx.x & 63;
  int g = lane >> 3, li = lane & 7;
  f32x2 acc[4];
  #pragma unroll
  for(int k=0;k<4;k++) acc[k] = (f32x2){0.f,0.f};
  int beg = rp[d], end = rp[d+1];
  int j = beg + g;
  bool h0 = j < end, h1 = j + 8 < end;
  int s0 = 0, s1 = 0;
  if(h0) s0 = srcs[j];
  if(h1) s1 = srcs[j+8];
  while(h1){
    int nj = j + 16;
    bool nh0 = nj < end, nh1 = nj + 8 < end;
    int ns0 = 0, ns1 = 0;
    if(nh0) ns0 = srcs[nj];
    if(nh1) ns1 = srcs[nj+8];
    uint4 v = *(const uint4*)(H2s + (size_t)s0*FP + li*8);
    uint4 u = *(const uint4*)(H2s + (size_t)s1*FP + li*8);
    acc[0] = pkadd(acc[0], pkadd(bfup(v.x), bfup(u.x)));
    acc[1] = pkadd(acc[1], pkadd(bfup(v.y), bfup(u.y)));
    acc[2] = pkadd(acc[2], pkadd(bfup(v.z), bfup(u.z)));
    acc[3] = pkadd(acc[3], pkadd(bfup(v.w), bfup(u.w)));
    j = nj; s0 = ns0; s1 = ns1; h0 = nh0; h1 = nh1;
  }
  if(h0){
    uint4 v = *(const uint4*)(H2s + (size_t)s0*FP + li*8);
    acc[0] = pkadd(acc[0], bfup(v.x));
    acc[1] = pkadd(acc[1], bfup(v.y));
    acc[2] = pkadd(acc[2], bfup(v.z));
    acc[3] = pkadd(acc[3], bfup(v.w));
  }
  #pragma unroll
  for(int k=0;k<4;k++){
    #pragma unroll
    for(int c=0;c<2;c++){
      acc[k][c] += __shfl_xor(acc[k][c], 8);
      acc[k][c] += __shfl_xor(acc[k][c], 16);
      acc[k][c] += __shfl_xor(acc[k][c], 32);
    }
  }
  uint4 sv = *(const uint4*)(H2s + (size_t)d*FP + li*8);
  uint32_t sd[4] = {sv.x, sv.y, sv.z, sv.w};
  float dd = dinv[d];
  float val[8];
  #pragma unroll
  for(int k=0;k<4;k++){
    f32x2 s2 = bfup(sd[k]);
    #pragma unroll
    for(int c=0;c<2;c++){
      int col = li*8 + k*2 + c;
      float bv = (col < FOUT) ? b2[col] : 0.f;
      val[k*2+c] = (col < FOUT) ? ((acc[k][c]+s2[c])*dd + bv) : -3.402823466e38f;
    }
  }
  float m = val[0];
  #pragma unroll
  for(int k=1;k<8;k++) m = fmaxf(m, val[k]);
  #pragma unroll
  for(int off=1; off<8; off<<=1) m = fmaxf(m, __shfl_xor(m, off));
  float ssum = 0.f;
  #pragma unroll
  for(int k=0;k<8;k++){
    int col = li*8 + k;
    ssum += (col < FOUT) ? expf(val[k] - m) : 0.f;
  }
  #pragma unroll
  for(int off=1; off<8; off<<=1) ssum += __shfl_xor(ssum, off);
  float lse = m + logf(ssum);
  if(g == 0 && li < 5){
    float4 o0 = {val[0]-lse, val[1]-lse, val[2]-lse, val[3]-lse};
    float4 o1 = {val[4]-lse, val[5]-lse, val[6]-lse, val[7]-lse};
    float* op = out + (size_t)d*FOUT + li*8;
    *(float4*)op = o0;
    *(float4*)(op+4) = o1;
  }
}

// ---------------- launch ----------------

extern "C" void kernel_launch(void* const* d_in, const int* in_sizes, int n_in,
                              void* d_out, int out_size, void* d_ws, size_t ws_size,
                              hipStream_t stream){
  const float* X  = (const float*)d_in[0];
  const int*   ei = (const int*)d_in[1];
  const float* W1 = (const float*)d_in[2];
  const float* b1 = (const float*)d_in[3];
  const float* W2 = (const float*)d_in[4];
  const float* b2 = (const float*)d_in[5];
  float* out = (float*)d_out;

  int n = in_sizes[0] / FIN;      // 100000
  int e = in_sizes[1] / 2;        // 1600000
  const int* src = ei;
  const int* dst = ei + e;

  // workspace layout
  ushort* XWs = (ushort*)d_ws;                       // n*128 bf16 (dinv-scaled XW)
  ushort* H1b = XWs + (size_t)n*FH;                  // n*128 bf16
  ushort* H2s = H1b + (size_t)n*FH;                  // n*64  bf16 (dinv-scaled, padded)
  ushort* W1t = H2s + (size_t)n*FP;                  // 128*512
  ushort* W2t = W1t + (size_t)FH*FIN;                // 48*128
  float* dinv = (float*)(W2t + 48*FH);               // n
  int* cnt    = (int*)(dinv + n);                    // n
  int* cursor = cnt + n;                             // n
  int* rp     = cursor + n;                          // n+1
  int* srcs   = rp + (n+1) + 3;                      // e
  int* aux    = srcs + e;                            // 256

  int nchunks = (n + 1023) / 1024;

  hipLaunchKernelGGL(k_init, dim3((2*n+255)/256), dim3(256), 0, stream, cnt, 2*n, W1, W2, W1t, W2t);
  hipLaunchKernelGGL(k_count, dim3((e+255)/256), dim3(256), 0, stream, dst, e, cnt);
  hipLaunchKernelGGL(k_scan_a, dim3(nchunks), dim3(256), 0, stream, cnt, n, rp, aux);
  hipLaunchKernelGGL(k_scan_b, dim3(1), dim3(256), 0, stream, aux, nchunks);
  hipLaunchKernelGGL(k_scan_c, dim3((n+255)/256), dim3(256), 0, stream, rp, aux, cnt, dinv, n);
  hipLaunchKernelGGL(k_fill, dim3((e+255)/256), dim3(256), 0, stream, src, dst, e, rp, cursor, srcs);

  hipLaunchKernelGGL(k_gemm1_mfma, dim3((n+255)/256), dim3(512), 0, stream, X, W1t, dinv, XWs, n);
  hipLaunchKernelGGL(k_agg1, dim3((n+3)/4), dim3(256), 0, stream, XWs, rp, srcs, dinv, b1, H1b, n);
  hipLaunchKernelGGL(k_gemm2_mfma, dim3((n+127)/128), dim3(256), 0, stream, H1b, W2t, dinv, H2s, n);
  hipLaunchKernelGGL(k_agg2_sm, dim3((n+3)/4), dim3(256), 0, stream, H2s, rp, srcs, dinv, b2, out, n);
}